// Round 1
// baseline (1042.313 us; speedup 1.0000x reference)
//
#include <hip/hip_runtime.h>
#include <math.h>

#define NTOK 21824
#define TM 32
#define NCLS 80
#define OUTC 84

__global__ __launch_bounds__(256) void dfd_head_kernel(
    const float* __restrict__ fm0, const float* __restrict__ fm1,
    const float* __restrict__ fm2, const float* __restrict__ fm3,
    const float* __restrict__ fm4,
    const float* __restrict__ cls_Wh, const float* __restrict__ cls_bh,
    const float* __restrict__ cls_Wo, const float* __restrict__ cls_bo,
    const float* __restrict__ box_Wh, const float* __restrict__ box_bh,
    const float* __restrict__ box_Wo, const float* __restrict__ box_bo,
    float* __restrict__ out)
{
    __shared__ float xs[256][TM];       // X tile, [k][t] — reads are broadcast
    __shared__ float hs[256][TM + 1];   // hidden, padded: kills stride-32 bank conflict
    __shared__ float outs[TM * OUTC];   // staged output tile (contiguous in global)

    const int tid = threadIdx.x;
    const int n0  = blockIdx.x * TM;
    const int bb  = blockIdx.y;

    // pyramid level for this tile (tiles never span levels: offsets are x64)
    int off, dim;
    const float* fm;
    if (n0 < 16384)      { off = 0;     dim = 128; fm = fm0; }
    else if (n0 < 20480) { off = 16384; dim = 64;  fm = fm1; }
    else if (n0 < 21504) { off = 20480; dim = 32;  fm = fm2; }
    else if (n0 < 21760) { off = 21504; dim = 16;  fm = fm3; }
    else                 { off = 21760; dim = 8;   fm = fm4; }
    const int hw = dim * dim;
    const int p0 = n0 - off;

    // ---- stage X tile: x[t][f] = fm[b, f, p0+t]  -> xs[f][t]
    {
        const size_t base = (size_t)bb * 256 * hw + p0;
        for (int i = tid; i < 256 * TM; i += 256) {
            const int t = i & (TM - 1);
            const int f = i >> 5;
            xs[f][t] = fm[base + (size_t)f * hw + t];
        }
    }
    __syncthreads();

    // ================= CLS MLP =================
    {   // hidden: thread u = tid computes hs[u][0..31]
        float acc[TM];
        #pragma unroll
        for (int t = 0; t < TM; ++t) acc[t] = 0.f;
        const float* wrow = cls_Wh + tid * 256;
        #pragma unroll 4
        for (int k = 0; k < 256; ++k) {
            const float w = wrow[k];
            #pragma unroll
            for (int t = 0; t < TM; ++t) acc[t] = fmaf(w, xs[k][t], acc[t]);
        }
        const float bh = cls_bh[tid];
        #pragma unroll
        for (int t = 0; t < TM; ++t) hs[tid][t] = fmaxf(acc[t] + bh, 0.f);
    }
    __syncthreads();

    // cls output layer: 32 t x 16 groups of 5 outputs = 512 items, 2/thread
    for (int i = tid; i < TM * 16; i += 256) {
        const int t  = i & (TM - 1);
        const int og = i >> 5;                // 0..15
        float acc[5] = {0.f, 0.f, 0.f, 0.f, 0.f};
        const float* w0 = cls_Wo + (og * 5) * 256;
        for (int k = 0; k < 256; ++k) {
            const float h = hs[k][t];
            #pragma unroll
            for (int j = 0; j < 5; ++j) acc[j] = fmaf(w0[j * 256 + k], h, acc[j]);
        }
        #pragma unroll
        for (int j = 0; j < 5; ++j)
            outs[t * OUTC + og * 5 + j] = acc[j] + cls_bo[og * 5 + j];
    }
    __syncthreads();   // cls layer-2 done reading hs before box overwrites it

    // ================= BOX MLP =================
    {
        float acc[TM];
        #pragma unroll
        for (int t = 0; t < TM; ++t) acc[t] = 0.f;
        const float* wrow = box_Wh + tid * 256;
        #pragma unroll 4
        for (int k = 0; k < 256; ++k) {
            const float w = wrow[k];
            #pragma unroll
            for (int t = 0; t < TM; ++t) acc[t] = fmaf(w, xs[k][t], acc[t]);
        }
        const float bh = box_bh[tid];
        #pragma unroll
        for (int t = 0; t < TM; ++t) hs[tid][t] = fmaxf(acc[t] + bh, 0.f);
    }
    __syncthreads();

    // box output layer + decode: 32 t x 4 outputs = 128 items
    if (tid < TM * 4) {
        const int t = tid & (TM - 1);
        const int o = tid >> 5;               // 0..3
        float acc = 0.f;
        const float* wrow = box_Wo + o * 256;
        for (int k = 0; k < 256; ++k) acc = fmaf(wrow[k], hs[k][t], acc);
        acc += box_bo[o];
        const float d = tanhf(acc);
        const int p = p0 + t;
        float val;
        if (o == 0)      val = ((float)(p % dim) + 0.5f) / dim + 0.1f * d;
        else if (o == 1) val = ((float)(p / dim) + 0.5f) / dim + 0.1f * d;
        else             val = exp2f(d) / dim;   // prior_wh * 2^delta, w==h==dim
        outs[t * OUTC + NCLS + o] = val;
    }
    __syncthreads();

    // ---- coalesced output write: tile is contiguous in [B, N, 84]
    const size_t obase = ((size_t)bb * NTOK + n0) * OUTC;
    for (int i = tid; i < TM * OUTC; i += 256) out[obase + i] = outs[i];
}

extern "C" void kernel_launch(void* const* d_in, const int* in_sizes, int n_in,
                              void* d_out, int out_size, void* d_ws, size_t ws_size,
                              hipStream_t stream) {
    dim3 grid(NTOK / TM, 8);   // 682 tiles x 8 batches
    dfd_head_kernel<<<grid, 256, 0, stream>>>(
        (const float*)d_in[0], (const float*)d_in[1], (const float*)d_in[2],
        (const float*)d_in[3], (const float*)d_in[4],
        (const float*)d_in[5], (const float*)d_in[6],
        (const float*)d_in[7], (const float*)d_in[8],
        (const float*)d_in[9], (const float*)d_in[10],
        (const float*)d_in[11], (const float*)d_in[12],
        (float*)d_out);
}

// Round 2
// 268.205 us; speedup vs baseline: 3.8863x; 3.8863x over previous
//
#include <hip/hip_runtime.h>
#include <math.h>
#include <stdint.h>

#define NTOK 21824

typedef __attribute__((ext_vector_type(8))) short bf16x8;
typedef __attribute__((ext_vector_type(4))) float f32x4;

union BFU { uint32_t w[4]; bf16x8 v; };

__device__ __forceinline__ uint32_t f2bf(float f) {
    uint32_t u = __builtin_bit_cast(uint32_t, f);
    return (u + 0x7FFFu + ((u >> 16) & 1u)) >> 16;   // RNE
}
__device__ __forceinline__ uint32_t pkbf(float lo, float hi) {
    return f2bf(lo) | (f2bf(hi) << 16);
}

// ws layout (uint16 elements): cls_Wh @0 (65536), box_Wh @65536, cls_Wo @131072 (20480),
// box_Wo padded to 16x256 @151552 (4096). total 155648.
#define WOFF_CWH 0
#define WOFF_BWH 65536
#define WOFF_CWO 131072
#define WOFF_BWO 151552

__global__ void prep_weights(const float* __restrict__ cWh, const float* __restrict__ cWo,
                             const float* __restrict__ bWh, const float* __restrict__ bWo,
                             uint16_t* __restrict__ ws) {
    int i = blockIdx.x * 256 + threadIdx.x;
    if (i >= 155648) return;
    uint32_t v;
    if (i < 65536)       v = f2bf(cWh[i]);
    else if (i < 131072) v = f2bf(bWh[i - 65536]);
    else if (i < 151552) v = f2bf(cWo[i - 131072]);
    else { int j = i - 151552; v = (j < 1024) ? f2bf(bWo[j]) : 0u; }
    ws[i] = (uint16_t)v;
}

__global__ __launch_bounds__(256, 2) void dfd_mfma(
    const float* __restrict__ fm0, const float* __restrict__ fm1,
    const float* __restrict__ fm2, const float* __restrict__ fm3,
    const float* __restrict__ fm4,
    const float* __restrict__ cls_bh, const float* __restrict__ cls_bo,
    const float* __restrict__ box_bh, const float* __restrict__ box_bo,
    const uint16_t* __restrict__ wbf,
    float* __restrict__ out)
{
    const int tid  = threadIdx.x;
    const int lane = tid & 63;
    const int wid  = tid >> 6;
    const int r    = lane & 15;      // MFMA col / A-row index
    const int q    = lane >> 4;      // 16-lane group
    const int n0   = (blockIdx.x * 4 + wid) * 32;   // batch-local token start
    if (n0 >= NTOK) return;
    const int b = blockIdx.y;

    // pyramid level (wave-uniform; 32-token ranges never span levels)
    const float* fm; int off, ls;
    if      (n0 < 16384) { fm = fm0; off = 0;     ls = 7; }
    else if (n0 < 20480) { fm = fm1; off = 16384; ls = 6; }
    else if (n0 < 21504) { fm = fm2; off = 20480; ls = 5; }
    else if (n0 < 21760) { fm = fm3; off = 21504; ls = 4; }
    else                 { fm = fm4; off = 21760; ls = 3; }
    const int dim = 1 << ls;
    const int hw  = dim * dim;
    const int p0  = n0 - off;

    // ---- X as B-fragments: B[k = kq*32 + q*8 + j][t = nt*16 + r], kept in regs for both heads
    uint32_t Xw[8][2][4];
    {
        const float* fmb = fm + (size_t)b * 256 * hw + p0 + r;
        #pragma unroll
        for (int kq = 0; kq < 8; ++kq) {
            #pragma unroll
            for (int nt = 0; nt < 2; ++nt) {
                const float* src = fmb + (size_t)(kq * 32 + q * 8) * hw + nt * 16;
                float x[8];
                #pragma unroll
                for (int j = 0; j < 8; ++j) x[j] = src[(size_t)j * hw];
                Xw[kq][nt][0] = pkbf(x[0], x[1]);
                Xw[kq][nt][1] = pkbf(x[2], x[3]);
                Xw[kq][nt][2] = pkbf(x[4], x[5]);
                Xw[kq][nt][3] = pkbf(x[6], x[7]);
            }
        }
    }

    uint32_t P[16][2][2];   // packed hidden: [m-tile][nt][jj-pair]
    const int  selb0   = ((q & 1) * 32 + r) * 4;   // bpermute byte sel: src lane 2*(q&1)*16 + r
    const int  selb1   = selb0 + 64;               // src lane +16
    const bool hi_half = (lane >= 32);

    auto xfrag = [&](int kq, int nt) -> bf16x8 {
        BFU u; u.w[0] = Xw[kq][nt][0]; u.w[1] = Xw[kq][nt][1];
               u.w[2] = Xw[kq][nt][2]; u.w[3] = Xw[kq][nt][3];
        return u.v;
    };

    // GEMM1: D[h][t] = W[h][k] * X[k][t]; lane holds D[m*16+q*4+jj][nt*16+r]
    auto run_g1 = [&](const uint16_t* Wh, const float* bh) {
        #pragma unroll
        for (int m = 0; m < 16; ++m) {
            f32x4 a0 = {0.f, 0.f, 0.f, 0.f}, a1 = {0.f, 0.f, 0.f, 0.f};
            const uint16_t* wrow = Wh + (m * 16 + r) * 256 + q * 8;
            #pragma unroll
            for (int kq = 0; kq < 8; ++kq) {
                bf16x8 af = *(const bf16x8*)(wrow + kq * 32);
                a0 = __builtin_amdgcn_mfma_f32_16x16x32_bf16(af, xfrag(kq, 0), a0, 0, 0, 0);
                a1 = __builtin_amdgcn_mfma_f32_16x16x32_bf16(af, xfrag(kq, 1), a1, 0, 0, 0);
            }
            const f32x4 bv = *(const f32x4*)(bh + m * 16 + q * 4);
            float h0[4], h1[4];
            #pragma unroll
            for (int jj = 0; jj < 4; ++jj) {
                h0[jj] = fmaxf(a0[jj] + bv[jj], 0.f);
                h1[jj] = fmaxf(a1[jj] + bv[jj], 0.f);
            }
            P[m][0][0] = pkbf(h0[0], h0[1]); P[m][0][1] = pkbf(h0[2], h0[3]);
            P[m][1][0] = pkbf(h1[0], h1[1]); P[m][1][1] = pkbf(h1[2], h1[3]);
        }
    };

    // Build GEMM2 B-fragment for k-step kq from packed hidden via in-register exchange:
    // element j (k2 = kq*32+q*8+j) lives in m-tile 2kq+(q>>1), src lane 2(q&1)+(j>>2), pair j&3.
    auto b2frag = [&](int kq, int nt) -> bf16x8 {
        BFU u;
        #pragma unroll
        for (int w = 0; w < 4; ++w) {
            const int pp  = w & 1;
            const int sel = (w & 2) ? selb1 : selb0;
            uint32_t lo = (uint32_t)__builtin_amdgcn_ds_bpermute(sel, (int)P[2 * kq][nt][pp]);
            uint32_t hi = (uint32_t)__builtin_amdgcn_ds_bpermute(sel, (int)P[2 * kq + 1][nt][pp]);
            u.w[w] = hi_half ? hi : lo;
        }
        return u.v;
    };

    // ================= CLS head =================
    run_g1(wbf + WOFF_CWH, cls_bh);
    {
        f32x4 c[5][2];
        #pragma unroll
        for (int m2 = 0; m2 < 5; ++m2) {
            c[m2][0] = {0.f, 0.f, 0.f, 0.f}; c[m2][1] = {0.f, 0.f, 0.f, 0.f};
        }
        const uint16_t* Wo = wbf + WOFF_CWO + r * 256 + q * 8;
        #pragma unroll
        for (int kq = 0; kq < 8; ++kq) {
            bf16x8 b0 = b2frag(kq, 0);
            bf16x8 b1 = b2frag(kq, 1);
            #pragma unroll
            for (int m2 = 0; m2 < 5; ++m2) {
                bf16x8 af = *(const bf16x8*)(Wo + m2 * 16 * 256 + kq * 32);
                c[m2][0] = __builtin_amdgcn_mfma_f32_16x16x32_bf16(af, b0, c[m2][0], 0, 0, 0);
                c[m2][1] = __builtin_amdgcn_mfma_f32_16x16x32_bf16(af, b1, c[m2][1], 0, 0, 0);
            }
        }
        #pragma unroll
        for (int m2 = 0; m2 < 5; ++m2) {
            const f32x4 bo = *(const f32x4*)(cls_bo + m2 * 16 + q * 4);
            #pragma unroll
            for (int nt = 0; nt < 2; ++nt) {
                f32x4 v;
                #pragma unroll
                for (int jj = 0; jj < 4; ++jj) v[jj] = c[m2][nt][jj] + bo[jj];
                *(f32x4*)(out + ((size_t)b * NTOK + n0 + nt * 16 + r) * 84 + m2 * 16 + q * 4) = v;
            }
        }
    }

    // ================= BOX head =================
    run_g1(wbf + WOFF_BWH, box_bh);
    {
        f32x4 c0 = {0.f, 0.f, 0.f, 0.f}, c1 = {0.f, 0.f, 0.f, 0.f};
        const uint16_t* Wo = wbf + WOFF_BWO + r * 256 + q * 8;
        #pragma unroll
        for (int kq = 0; kq < 8; ++kq) {
            bf16x8 af = *(const bf16x8*)(Wo + kq * 32);
            c0 = __builtin_amdgcn_mfma_f32_16x16x32_bf16(af, b2frag(kq, 0), c0, 0, 0, 0);
            c1 = __builtin_amdgcn_mfma_f32_16x16x32_bf16(af, b2frag(kq, 1), c1, 0, 0, 0);
        }
        if (lane < 16) {   // q==0 holds c = 0..3 (rows 4..15 of padded Wo are zero)
            const f32x4 bo = *(const f32x4*)box_bo;
            const float inv = 1.f / (float)dim;
            #pragma unroll
            for (int nt = 0; nt < 2; ++nt) {
                const f32x4 cc = nt ? c1 : c0;
                const int p = p0 + nt * 16 + r;
                const float d0 = tanhf(cc[0] + bo[0]);
                const float d1 = tanhf(cc[1] + bo[1]);
                const float d2 = tanhf(cc[2] + bo[2]);
                const float d3 = tanhf(cc[3] + bo[3]);
                f32x4 v;
                v[0] = ((float)(p & (dim - 1)) + 0.5f) * inv + 0.1f * d0;
                v[1] = ((float)(p >> ls) + 0.5f) * inv + 0.1f * d1;
                v[2] = exp2f(d2) * inv;
                v[3] = exp2f(d3) * inv;
                *(f32x4*)(out + ((size_t)b * NTOK + n0 + nt * 16 + r) * 84 + 80) = v;
            }
        }
    }
}

extern "C" void kernel_launch(void* const* d_in, const int* in_sizes, int n_in,
                              void* d_out, int out_size, void* d_ws, size_t ws_size,
                              hipStream_t stream) {
    uint16_t* ws = (uint16_t*)d_ws;
    prep_weights<<<608, 256, 0, stream>>>(
        (const float*)d_in[5],  (const float*)d_in[7],
        (const float*)d_in[9],  (const float*)d_in[11], ws);
    dim3 grid((682 + 3) / 4, 8);   // 682 waves of 32 tokens per batch, 4 waves/block
    dfd_mfma<<<grid, 256, 0, stream>>>(
        (const float*)d_in[0], (const float*)d_in[1], (const float*)d_in[2],
        (const float*)d_in[3], (const float*)d_in[4],
        (const float*)d_in[6],  (const float*)d_in[8],
        (const float*)d_in[10], (const float*)d_in[12],
        ws, (float*)d_out);
}

// Round 3
// 237.452 us; speedup vs baseline: 4.3896x; 1.1295x over previous
//
#include <hip/hip_runtime.h>
#include <math.h>
#include <stdint.h>

#define NTOK 21824

typedef __attribute__((ext_vector_type(8))) short bf16x8;
typedef __attribute__((ext_vector_type(4))) float f32x4;

union BFU { uint32_t w[4]; bf16x8 v; };

__device__ __forceinline__ uint32_t f2bf(float f) {
    uint32_t u = __builtin_bit_cast(uint32_t, f);
    return (u + 0x7FFFu + ((u >> 16) & 1u)) >> 16;   // RNE
}
__device__ __forceinline__ uint32_t pkbf(float lo, float hi) {
    return f2bf(lo) | (f2bf(hi) << 16);
}

// ws layout (uint16): cls_Wh @0, box_Wh @65536, cls_Wo @131072, box_Wo(pad 16x256) @151552
#define WOFF_CWH 0
#define WOFF_BWH 65536
#define WOFF_CWO 131072
#define WOFF_BWO 151552

__global__ void prep_weights(const float* __restrict__ cWh, const float* __restrict__ cWo,
                             const float* __restrict__ bWh, const float* __restrict__ bWo,
                             uint16_t* __restrict__ ws) {
    int i = blockIdx.x * 256 + threadIdx.x;
    if (i >= 155648) return;
    uint32_t v;
    if (i < 65536)       v = f2bf(cWh[i]);
    else if (i < 131072) v = f2bf(bWh[i - 65536]);
    else if (i < 151552) v = f2bf(cWo[i - 131072]);
    else { int j = i - 151552; v = (j < 1024) ? f2bf(bWo[j]) : 0u; }
    ws[i] = (uint16_t)v;
}

__global__ __launch_bounds__(256, 3) void dfd_mfma(
    const float* __restrict__ fm0, const float* __restrict__ fm1,
    const float* __restrict__ fm2, const float* __restrict__ fm3,
    const float* __restrict__ fm4,
    const float* __restrict__ cls_bh, const float* __restrict__ cls_bo,
    const float* __restrict__ box_bh, const float* __restrict__ box_bo,
    const uint16_t* __restrict__ wbf,
    float* __restrict__ out)
{
    const int tid  = threadIdx.x;
    const int lane = tid & 63;
    const int wid  = tid >> 6;
    const int r    = lane & 15;
    const int q    = lane >> 4;
    // wave pair: (tile, head). head 0 = cls, 1 = box. Twin waves share X via L1.
    const int tile = blockIdx.x * 2 + (wid >> 1);
    const int head = wid & 1;
    const int n0   = tile * 32;
    const int b    = blockIdx.y;

    // pyramid level (wave-uniform; 32-token tiles never span levels)
    const float* fm; int off, ls;
    if      (n0 < 16384) { fm = fm0; off = 0;     ls = 7; }
    else if (n0 < 20480) { fm = fm1; off = 16384; ls = 6; }
    else if (n0 < 21504) { fm = fm2; off = 20480; ls = 5; }
    else if (n0 < 21760) { fm = fm3; off = 21504; ls = 4; }
    else                 { fm = fm4; off = 21760; ls = 3; }
    const int dim = 1 << ls;
    const int hw  = dim * dim;
    const int p0  = n0 - off;

    // ---- X as B-fragments: B[k = kq*32 + q*8 + j][t = nt*16 + r]
    uint32_t Xw[8][2][4];
    {
        const float* fmb = fm + (size_t)b * 256 * hw + p0 + r;
        #pragma unroll
        for (int kq = 0; kq < 8; ++kq) {
            #pragma unroll
            for (int nt = 0; nt < 2; ++nt) {
                const float* src = fmb + (size_t)(kq * 32 + q * 8) * hw + nt * 16;
                float x[8];
                #pragma unroll
                for (int j = 0; j < 8; ++j) x[j] = src[(size_t)j * hw];
                Xw[kq][nt][0] = pkbf(x[0], x[1]);
                Xw[kq][nt][1] = pkbf(x[2], x[3]);
                Xw[kq][nt][2] = pkbf(x[4], x[5]);
                Xw[kq][nt][3] = pkbf(x[6], x[7]);
            }
        }
    }

    const int  selb0   = ((q & 1) * 32 + r) * 4;
    const int  selb1   = selb0 + 64;
    const bool hi_half = (lane >= 32);

    auto xfrag = [&](int kq, int nt) -> bf16x8 {
        BFU u; u.w[0] = Xw[kq][nt][0]; u.w[1] = Xw[kq][nt][1];
               u.w[2] = Xw[kq][nt][2]; u.w[3] = Xw[kq][nt][3];
        return u.v;
    };

    // GEMM1 one m-tile: full-K sweep, bias+ReLU, pack to bf16 pairs
    auto g1_step = [&](const uint16_t* Wh, const float* bh, int m, uint32_t Pm[2][2]) {
        f32x4 a0 = {0.f, 0.f, 0.f, 0.f}, a1 = {0.f, 0.f, 0.f, 0.f};
        const uint16_t* wrow = Wh + (m * 16 + r) * 256 + q * 8;
        #pragma unroll
        for (int k1 = 0; k1 < 8; ++k1) {
            bf16x8 af = *(const bf16x8*)(wrow + k1 * 32);
            a0 = __builtin_amdgcn_mfma_f32_16x16x32_bf16(af, xfrag(k1, 0), a0, 0, 0, 0);
            a1 = __builtin_amdgcn_mfma_f32_16x16x32_bf16(af, xfrag(k1, 1), a1, 0, 0, 0);
        }
        const f32x4 bv = *(const f32x4*)(bh + m * 16 + q * 4);
        Pm[0][0] = pkbf(fmaxf(a0[0] + bv[0], 0.f), fmaxf(a0[1] + bv[1], 0.f));
        Pm[0][1] = pkbf(fmaxf(a0[2] + bv[2], 0.f), fmaxf(a0[3] + bv[3], 0.f));
        Pm[1][0] = pkbf(fmaxf(a1[0] + bv[0], 0.f), fmaxf(a1[1] + bv[1], 0.f));
        Pm[1][1] = pkbf(fmaxf(a1[2] + bv[2], 0.f), fmaxf(a1[3] + bv[3], 0.f));
    };

    // GEMM2 B-fragment for this kq from the two fresh m-tiles (in-register exchange)
    auto b2frag = [&](const uint32_t P0[2][2], const uint32_t P1[2][2], int nt) -> bf16x8 {
        BFU u;
        #pragma unroll
        for (int w = 0; w < 4; ++w) {
            const int pp  = w & 1;
            const int sel = (w & 2) ? selb1 : selb0;
            uint32_t lo = (uint32_t)__builtin_amdgcn_ds_bpermute(sel, (int)P0[nt][pp]);
            uint32_t hi = (uint32_t)__builtin_amdgcn_ds_bpermute(sel, (int)P1[nt][pp]);
            u.w[w] = hi_half ? hi : lo;
        }
        return u.v;
    };

    if (head == 0) {
        // ================= CLS wave =================
        f32x4 c[5][2];
        #pragma unroll
        for (int m2 = 0; m2 < 5; ++m2) {
            c[m2][0] = {0.f, 0.f, 0.f, 0.f}; c[m2][1] = {0.f, 0.f, 0.f, 0.f};
        }
        for (int kq = 0; kq < 8; ++kq) {
            uint32_t P0[2][2], P1[2][2];
            g1_step(wbf + WOFF_CWH, cls_bh, 2 * kq,     P0);
            g1_step(wbf + WOFF_CWH, cls_bh, 2 * kq + 1, P1);
            bf16x8 b0 = b2frag(P0, P1, 0);
            bf16x8 b1 = b2frag(P0, P1, 1);
            const uint16_t* Wo = wbf + WOFF_CWO + r * 256 + q * 8 + kq * 32;
            #pragma unroll
            for (int m2 = 0; m2 < 5; ++m2) {
                bf16x8 af = *(const bf16x8*)(Wo + m2 * 16 * 256);
                c[m2][0] = __builtin_amdgcn_mfma_f32_16x16x32_bf16(af, b0, c[m2][0], 0, 0, 0);
                c[m2][1] = __builtin_amdgcn_mfma_f32_16x16x32_bf16(af, b1, c[m2][1], 0, 0, 0);
            }
        }
        #pragma unroll
        for (int m2 = 0; m2 < 5; ++m2) {
            const f32x4 bo = *(const f32x4*)(cls_bo + m2 * 16 + q * 4);
            #pragma unroll
            for (int nt = 0; nt < 2; ++nt) {
                f32x4 v;
                #pragma unroll
                for (int jj = 0; jj < 4; ++jj) v[jj] = c[m2][nt][jj] + bo[jj];
                *(f32x4*)(out + ((size_t)b * NTOK + n0 + nt * 16 + r) * 84 + m2 * 16 + q * 4) = v;
            }
        }
    } else {
        // ================= BOX wave =================
        f32x4 c0 = {0.f, 0.f, 0.f, 0.f}, c1 = {0.f, 0.f, 0.f, 0.f};
        for (int kq = 0; kq < 8; ++kq) {
            uint32_t P0[2][2], P1[2][2];
            g1_step(wbf + WOFF_BWH, box_bh, 2 * kq,     P0);
            g1_step(wbf + WOFF_BWH, box_bh, 2 * kq + 1, P1);
            bf16x8 af = *(const bf16x8*)(wbf + WOFF_BWO + r * 256 + q * 8 + kq * 32);
            c0 = __builtin_amdgcn_mfma_f32_16x16x32_bf16(af, b2frag(P0, P1, 0), c0, 0, 0, 0);
            c1 = __builtin_amdgcn_mfma_f32_16x16x32_bf16(af, b2frag(P0, P1, 1), c1, 0, 0, 0);
        }
        if (lane < 16) {   // q==0 holds rows 0..3 (padded Wo rows 4..15 are zero)
            const f32x4 bo = *(const f32x4*)box_bo;
            const float inv = 1.f / (float)dim;
            #pragma unroll
            for (int nt = 0; nt < 2; ++nt) {
                const f32x4 cc = nt ? c1 : c0;
                const int p = p0 + nt * 16 + r;
                const float d0 = tanhf(cc[0] + bo[0]);
                const float d1 = tanhf(cc[1] + bo[1]);
                const float d2 = tanhf(cc[2] + bo[2]);
                const float d3 = tanhf(cc[3] + bo[3]);
                f32x4 v;
                v[0] = ((float)(p & (dim - 1)) + 0.5f) * inv + 0.1f * d0;
                v[1] = ((float)(p >> ls) + 0.5f) * inv + 0.1f * d1;
                v[2] = exp2f(d2) * inv;
                v[3] = exp2f(d3) * inv;
                *(f32x4*)(out + ((size_t)b * NTOK + n0 + nt * 16 + r) * 84 + 80) = v;
            }
        }
    }
}

extern "C" void kernel_launch(void* const* d_in, const int* in_sizes, int n_in,
                              void* d_out, int out_size, void* d_ws, size_t ws_size,
                              hipStream_t stream) {
    uint16_t* ws = (uint16_t*)d_ws;
    prep_weights<<<608, 256, 0, stream>>>(
        (const float*)d_in[5],  (const float*)d_in[7],
        (const float*)d_in[9],  (const float*)d_in[11], ws);
    dim3 grid(341, 8);   // 682 tiles/batch, 2 tiles x 2 heads = 4 waves/block
    dfd_mfma<<<grid, 256, 0, stream>>>(
        (const float*)d_in[0], (const float*)d_in[1], (const float*)d_in[2],
        (const float*)d_in[3], (const float*)d_in[4],
        (const float*)d_in[6],  (const float*)d_in[8],
        (const float*)d_in[10], (const float*)d_in[12],
        ws, (float*)d_out);
}

// Round 4
// 175.469 us; speedup vs baseline: 5.9402x; 1.3532x over previous
//
#include <hip/hip_runtime.h>
#include <math.h>
#include <stdint.h>

#define NTOK 21824

typedef __attribute__((ext_vector_type(8))) short bf16x8;
typedef __attribute__((ext_vector_type(4))) float f32x4;

__device__ __forceinline__ uint32_t f2bf(float f) {
    uint32_t u = __builtin_bit_cast(uint32_t, f);
    return (u + 0x7FFFu + ((u >> 16) & 1u)) >> 16;   // RNE
}

// ws layout (uint16): cls_Wh @0, box_Wh @65536, cls_Wo @131072, box_Wo(pad 16x256) @151552
#define WOFF_CWH 0
#define WOFF_BWH 65536
#define WOFF_CWO 131072
#define WOFF_BWO 151552

__global__ void prep_weights(const float* __restrict__ cWh, const float* __restrict__ cWo,
                             const float* __restrict__ bWh, const float* __restrict__ bWo,
                             uint16_t* __restrict__ ws) {
    int i = blockIdx.x * 256 + threadIdx.x;
    if (i >= 155648) return;
    uint32_t v;
    if (i < 65536)       v = f2bf(cWh[i]);
    else if (i < 131072) v = f2bf(bWh[i - 65536]);
    else if (i < 151552) v = f2bf(cWo[i - 131072]);
    else { int j = i - 151552; v = (j < 1024) ? f2bf(bWo[j]) : 0u; }
    ws[i] = (uint16_t)v;
}

__global__ __launch_bounds__(512, 2) void dfd_fused(
    const float* __restrict__ fm0, const float* __restrict__ fm1,
    const float* __restrict__ fm2, const float* __restrict__ fm3,
    const float* __restrict__ fm4,
    const float* __restrict__ cls_bh, const float* __restrict__ cls_bo,
    const float* __restrict__ box_bh, const float* __restrict__ box_bo,
    const uint16_t* __restrict__ wbf,
    float* __restrict__ out)
{
    __shared__ uint16_t Xs[64 * 256];   // [t][k], swizzle: k ^ ((t&7)<<3)
    __shared__ uint16_t Hs[64 * 512];   // [t][hh], hh = head*256 + h, same swizzle

    const int tid  = threadIdx.x;
    const int lane = tid & 63;
    const int w    = tid >> 6;          // wave 0..7
    const int r    = lane & 15;
    const int q    = lane >> 4;
    const int n0   = blockIdx.x * 64;   // 64-token tile (levels all divide by 64)
    const int b    = blockIdx.y;

    const float* fm; int off, ls;
    if      (n0 < 16384) { fm = fm0; off = 0;     ls = 7; }
    else if (n0 < 20480) { fm = fm1; off = 16384; ls = 6; }
    else if (n0 < 21504) { fm = fm2; off = 20480; ls = 5; }
    else if (n0 < 21760) { fm = fm3; off = 21504; ls = 4; }
    else                 { fm = fm4; off = 21760; ls = 3; }
    const int dim = 1 << ls;
    const int hw  = dim * dim;
    const int p0  = n0 - off;

    // ---- stage X tile: fm[b][f][p0+t] -> Xs[t][f] (bf16, swizzled), coalesced float4
    {
        const int f  = tid >> 1;             // 2 threads per feature row
        const int th = (tid & 1) * 32;       // half of the 64 tokens
        const float* src = fm + ((size_t)b * 256 + f) * hw + p0 + th;
        #pragma unroll
        for (int j = 0; j < 8; ++j) {
            const f32x4 v = *(const f32x4*)(src + j * 4);
            const int t0 = th + j * 4;
            #pragma unroll
            for (int e = 0; e < 4; ++e) {
                const int t = t0 + e;
                Xs[t * 256 + (f ^ ((t & 7) << 3))] = (uint16_t)f2bf(v[e]);
            }
        }
    }
    __syncthreads();

    // ---- G1 (both heads): wave w -> hidden rows [w*32, w*32+32) for cls AND box
    {
        f32x4 acc[4][4];
        #pragma unroll
        for (int m = 0; m < 4; ++m)
            #pragma unroll
            for (int l = 0; l < 4; ++l) acc[m][l] = {0.f, 0.f, 0.f, 0.f};

        const int rowoff = (w * 32 + r) * 256 + q * 8;
        const uint16_t* Bc0 = wbf + WOFF_CWH + rowoff;   // cls rows 2w*16
        const uint16_t* Bc1 = Bc0 + 4096;                // cls rows 2w*16+16
        const uint16_t* Bb0 = wbf + WOFF_BWH + rowoff;   // box
        const uint16_t* Bb1 = Bb0 + 4096;

        #pragma unroll
        for (int kq = 0; kq < 8; ++kq) {
            const bf16x8 bc0 = *(const bf16x8*)(Bc0 + kq * 32);
            const bf16x8 bc1 = *(const bf16x8*)(Bc1 + kq * 32);
            const bf16x8 bb0 = *(const bf16x8*)(Bb0 + kq * 32);
            const bf16x8 bb1 = *(const bf16x8*)(Bb1 + kq * 32);
            const int kcol = (kq * 32 + q * 8) ^ ((r & 7) << 3);
            #pragma unroll
            for (int m = 0; m < 4; ++m) {
                const bf16x8 a = *(const bf16x8*)&Xs[(m * 16 + r) * 256 + kcol];
                acc[m][0] = __builtin_amdgcn_mfma_f32_16x16x32_bf16(a, bc0, acc[m][0], 0, 0, 0);
                acc[m][1] = __builtin_amdgcn_mfma_f32_16x16x32_bf16(a, bc1, acc[m][1], 0, 0, 0);
                acc[m][2] = __builtin_amdgcn_mfma_f32_16x16x32_bf16(a, bb0, acc[m][2], 0, 0, 0);
                acc[m][3] = __builtin_amdgcn_mfma_f32_16x16x32_bf16(a, bb1, acc[m][3], 0, 0, 0);
            }
        }
        const float bcls0 = cls_bh[w * 32 + r];
        const float bcls1 = cls_bh[w * 32 + 16 + r];
        const float bbox0 = box_bh[w * 32 + r];
        const float bbox1 = box_bh[w * 32 + 16 + r];
        const int hc0 = w * 32 + r;
        #pragma unroll
        for (int m = 0; m < 4; ++m) {
            #pragma unroll
            for (int jj = 0; jj < 4; ++jj) {
                const int t  = m * 16 + q * 4 + jj;    // D row = token
                const int sw = (t & 7) << 3;
                uint16_t* row = &Hs[t * 512];
                row[(hc0)            ^ sw] = (uint16_t)f2bf(fmaxf(acc[m][0][jj] + bcls0, 0.f));
                row[(hc0 + 16)       ^ sw] = (uint16_t)f2bf(fmaxf(acc[m][1][jj] + bcls1, 0.f));
                row[(256 + hc0)      ^ sw] = (uint16_t)f2bf(fmaxf(acc[m][2][jj] + bbox0, 0.f));
                row[(256 + hc0 + 16) ^ sw] = (uint16_t)f2bf(fmaxf(acc[m][3][jj] + bbox1, 0.f));
            }
        }
    }
    __syncthreads();

    // ---- G2: waves 0-4 = cls out-tile w (cols w*16..+15, 4 M-tiles);
    //          waves 5,6 = box (M-tiles {0,1} / {2,3}) + decode
    if (w < 5) {
        f32x4 c[4];
        #pragma unroll
        for (int m = 0; m < 4; ++m) c[m] = {0.f, 0.f, 0.f, 0.f};
        const uint16_t* Bw = wbf + WOFF_CWO + (w * 16 + r) * 256 + q * 8;
        #pragma unroll
        for (int kq = 0; kq < 8; ++kq) {
            const bf16x8 bfr = *(const bf16x8*)(Bw + kq * 32);
            const int kcol = (kq * 32 + q * 8) ^ ((r & 7) << 3);
            #pragma unroll
            for (int m = 0; m < 4; ++m) {
                const bf16x8 a = *(const bf16x8*)&Hs[(m * 16 + r) * 512 + kcol];
                c[m] = __builtin_amdgcn_mfma_f32_16x16x32_bf16(a, bfr, c[m], 0, 0, 0);
            }
        }
        const float bo_l = cls_bo[w * 16 + r];
        #pragma unroll
        for (int m = 0; m < 4; ++m)
            #pragma unroll
            for (int jj = 0; jj < 4; ++jj)
                out[((size_t)b * NTOK + n0 + m * 16 + q * 4 + jj) * 84 + w * 16 + r]
                    = c[m][jj] + bo_l;
    } else if (w < 7) {
        const int m0 = (w - 5) * 2;   // wave 5: Mt 0,1; wave 6: Mt 2,3
        f32x4 c[2];
        c[0] = {0.f, 0.f, 0.f, 0.f}; c[1] = {0.f, 0.f, 0.f, 0.f};
        const uint16_t* Bw = wbf + WOFF_BWO + r * 256 + q * 8;
        #pragma unroll
        for (int kq = 0; kq < 8; ++kq) {
            const bf16x8 bfr = *(const bf16x8*)(Bw + kq * 32);
            const int kcol = 256 + ((kq * 32 + q * 8) ^ ((r & 7) << 3));
            #pragma unroll
            for (int mm = 0; mm < 2; ++mm) {
                const bf16x8 a = *(const bf16x8*)&Hs[((m0 + mm) * 16 + r) * 512 + kcol];
                c[mm] = __builtin_amdgcn_mfma_f32_16x16x32_bf16(a, bfr, c[mm], 0, 0, 0);
            }
        }
        if (r < 4) {   // only cols 0..3 are real box outputs (rows 4..15 of padded Wo = 0)
            const float bo_l = box_bo[r];
            const float inv  = 1.0f / (float)dim;
            #pragma unroll
            for (int mm = 0; mm < 2; ++mm)
                #pragma unroll
                for (int jj = 0; jj < 4; ++jj) {
                    const int t = (m0 + mm) * 16 + q * 4 + jj;
                    const int p = p0 + t;
                    const float d = tanhf(c[mm][jj] + bo_l);
                    float val;
                    if (r == 0)      val = ((float)(p & (dim - 1)) + 0.5f) * inv + 0.1f * d;
                    else if (r == 1) val = ((float)(p >> ls) + 0.5f) * inv + 0.1f * d;
                    else             val = exp2f(d) * inv;
                    out[((size_t)b * NTOK + n0 + t) * 84 + 80 + r] = val;
                }
        }
    }
}

extern "C" void kernel_launch(void* const* d_in, const int* in_sizes, int n_in,
                              void* d_out, int out_size, void* d_ws, size_t ws_size,
                              hipStream_t stream) {
    uint16_t* ws = (uint16_t*)d_ws;
    prep_weights<<<608, 256, 0, stream>>>(
        (const float*)d_in[5],  (const float*)d_in[7],
        (const float*)d_in[9],  (const float*)d_in[11], ws);
    dim3 grid(NTOK / 64, 8);   // 341 x 8 blocks, 512 threads
    dfd_fused<<<grid, 512, 0, stream>>>(
        (const float*)d_in[0], (const float*)d_in[1], (const float*)d_in[2],
        (const float*)d_in[3], (const float*)d_in[4],
        (const float*)d_in[6],  (const float*)d_in[8],
        (const float*)d_in[10], (const float*)d_in[12],
        ws, (float*)d_out);
}

// Round 5
// 136.279 us; speedup vs baseline: 7.6484x; 1.2876x over previous
//
#include <hip/hip_runtime.h>
#include <math.h>
#include <stdint.h>

#define NTOK 21824

typedef __attribute__((ext_vector_type(8)))  short bf16x8;
typedef __attribute__((ext_vector_type(4)))  float f32x4;
typedef __attribute__((ext_vector_type(16))) float f32x16;

__device__ __forceinline__ uint32_t f2bf(float f) {
    uint32_t u = __builtin_bit_cast(uint32_t, f);
    return (u + 0x7FFFu + ((u >> 16) & 1u)) >> 16;   // RNE
}
__device__ __forceinline__ uint32_t pkbf(float lo, float hi) {
    return f2bf(lo) | (f2bf(hi) << 16);
}

// ws layout (uint16): cls_Wh @0, box_Wh @65536, cls_Wo @131072, box_Wo(pad 16x256) @151552
#define WOFF_CWH 0
#define WOFF_BWH 65536
#define WOFF_CWO 131072
#define WOFF_BWO 151552

__global__ void prep_weights(const float* __restrict__ cWh, const float* __restrict__ cWo,
                             const float* __restrict__ bWh, const float* __restrict__ bWo,
                             uint16_t* __restrict__ ws) {
    int i = blockIdx.x * 256 + threadIdx.x;
    if (i >= 155648) return;
    uint32_t v;
    if (i < 65536)       v = f2bf(cWh[i]);
    else if (i < 131072) v = f2bf(bWh[i - 65536]);
    else if (i < 151552) v = f2bf(cWo[i - 131072]);
    else { int j = i - 151552; v = (j < 1024) ? f2bf(bWo[j]) : 0u; }
    ws[i] = (uint16_t)v;
}

__global__ __launch_bounds__(512, 4) void dfd_fused(
    const float* __restrict__ fm0, const float* __restrict__ fm1,
    const float* __restrict__ fm2, const float* __restrict__ fm3,
    const float* __restrict__ fm4,
    const float* __restrict__ cls_bh, const float* __restrict__ cls_bo,
    const float* __restrict__ box_bh, const float* __restrict__ box_bo,
    const uint16_t* __restrict__ wbf,
    float* __restrict__ out)
{
    // 64 KB overlay: phase 1-2 uses Xs[64][256]; phase 3-4 reuses as Hs[64][512]
    __shared__ uint16_t LB[64 * 512];
    uint16_t* Xs = LB;
    uint16_t* Hs = LB;

    const int tid  = threadIdx.x;
    const int lane = tid & 63;
    const int w    = tid >> 6;          // wave 0..7
    const int r    = lane & 15;
    const int q    = lane >> 4;
    const int n0   = blockIdx.x * 64;
    const int b    = blockIdx.y;

    const float* fm; int off, ls;
    if      (n0 < 16384) { fm = fm0; off = 0;     ls = 7; }
    else if (n0 < 20480) { fm = fm1; off = 16384; ls = 6; }
    else if (n0 < 21504) { fm = fm2; off = 20480; ls = 5; }
    else if (n0 < 21760) { fm = fm3; off = 21504; ls = 4; }
    else                 { fm = fm4; off = 21760; ls = 3; }
    const int dim = 1 << ls;
    const int hw  = dim * dim;
    const int p0  = n0 - off;

    // ---- stage: fm[b][f][p0+t] -> Xs[t][f^sw] bf16, b64 packed writes
    {
        const int t  = lane;                 // 64 tokens = 64 lanes
        const int sw = (t & 7) << 3;
        const float* src = fm + (size_t)b * 256 * hw + p0 + t;
        #pragma unroll
        for (int i = 0; i < 8; ++i) {
            const int f = w * 4 + i * 32;
            const float x0 = src[(size_t)(f + 0) * hw];
            const float x1 = src[(size_t)(f + 1) * hw];
            const float x2 = src[(size_t)(f + 2) * hw];
            const float x3 = src[(size_t)(f + 3) * hw];
            uint2 pk; pk.x = pkbf(x0, x1); pk.y = pkbf(x2, x3);
            *reinterpret_cast<uint2*>(&Xs[t * 256 + (f ^ sw)]) = pk;
        }
    }
    __syncthreads();

    // ---- G1 (32x32x16, both heads): wave w -> hidden cols [w*32, w*32+32)
    f32x16 acc[2][2];   // [m-tile][head]
    {
        #pragma unroll
        for (int mt = 0; mt < 2; ++mt)
            #pragma unroll
            for (int h = 0; h < 2; ++h)
                #pragma unroll
                for (int e = 0; e < 16; ++e) acc[mt][h][e] = 0.f;

        const int col = lane & 31;           // A-row (token) and B-col (hidden) index
        const int kh  = (lane >> 5) * 8;     // k-offset within 16-wide k-step
        const uint16_t* Wc = wbf + WOFF_CWH + (w * 32 + col) * 256 + kh;
        const uint16_t* Wb = wbf + WOFF_BWH + (w * 32 + col) * 256 + kh;

        #pragma unroll
        for (int ks = 0; ks < 16; ++ks) {
            const bf16x8 bc = *(const bf16x8*)(Wc + ks * 16);
            const bf16x8 bb = *(const bf16x8*)(Wb + ks * 16);
            #pragma unroll
            for (int mt = 0; mt < 2; ++mt) {
                const int t = mt * 32 + col;
                const int k = (ks * 16 + kh) ^ ((t & 7) << 3);
                const bf16x8 a = *(const bf16x8*)&Xs[t * 256 + k];
                acc[mt][0] = __builtin_amdgcn_mfma_f32_32x32x16_bf16(a, bc, acc[mt][0], 0, 0, 0);
                acc[mt][1] = __builtin_amdgcn_mfma_f32_32x32x16_bf16(a, bb, acc[mt][1], 0, 0, 0);
            }
        }
    }
    __syncthreads();   // all Xs reads complete before Hs overwrites

    // ---- write hidden (bias+ReLU) into Hs[t][hh^sw]
    {
        const int col  = lane & 31;
        const float bc = cls_bh[w * 32 + col];
        const float bbx = box_bh[w * 32 + col];
        #pragma unroll
        for (int mt = 0; mt < 2; ++mt) {
            #pragma unroll
            for (int reg = 0; reg < 16; ++reg) {
                const int t  = mt * 32 + (reg & 3) + 8 * (reg >> 2) + 4 * (lane >> 5);
                const int sw = (t & 7) << 3;
                const int hh = w * 32 + col;
                Hs[t * 512 + ((hh)       ^ sw)] = (uint16_t)f2bf(fmaxf(acc[mt][0][reg] + bc, 0.f));
                Hs[t * 512 + ((256 + hh) ^ sw)] = (uint16_t)f2bf(fmaxf(acc[mt][1][reg] + bbx, 0.f));
            }
        }
    }
    __syncthreads();

    // ---- G2 (16x16x32): waves 0-4 = cls out-tile w; waves 5,6 = box + decode
    if (w < 5) {
        f32x4 c[4];
        #pragma unroll
        for (int m = 0; m < 4; ++m) c[m] = {0.f, 0.f, 0.f, 0.f};
        const uint16_t* Bw = wbf + WOFF_CWO + (w * 16 + r) * 256 + q * 8;
        #pragma unroll
        for (int kq = 0; kq < 8; ++kq) {
            const bf16x8 bfr = *(const bf16x8*)(Bw + kq * 32);
            #pragma unroll
            for (int m = 0; m < 4; ++m) {
                const int t = m * 16 + r;
                const int kcol = (kq * 32 + q * 8) ^ ((t & 7) << 3);
                const bf16x8 a = *(const bf16x8*)&Hs[t * 512 + kcol];
                c[m] = __builtin_amdgcn_mfma_f32_16x16x32_bf16(a, bfr, c[m], 0, 0, 0);
            }
        }
        const float bo_l = cls_bo[w * 16 + r];
        #pragma unroll
        for (int m = 0; m < 4; ++m)
            #pragma unroll
            for (int jj = 0; jj < 4; ++jj)
                out[((size_t)b * NTOK + n0 + m * 16 + q * 4 + jj) * 84 + w * 16 + r]
                    = c[m][jj] + bo_l;
    } else if (w < 7) {
        const int m0 = (w - 5) * 2;
        f32x4 c[2];
        c[0] = {0.f, 0.f, 0.f, 0.f}; c[1] = {0.f, 0.f, 0.f, 0.f};
        const uint16_t* Bw = wbf + WOFF_BWO + r * 256 + q * 8;
        #pragma unroll
        for (int kq = 0; kq < 8; ++kq) {
            const bf16x8 bfr = *(const bf16x8*)(Bw + kq * 32);
            #pragma unroll
            for (int mm = 0; mm < 2; ++mm) {
                const int t = (m0 + mm) * 16 + r;
                const int kcol = 256 + ((kq * 32 + q * 8) ^ ((t & 7) << 3));
                const bf16x8 a = *(const bf16x8*)&Hs[t * 512 + kcol];
                c[mm] = __builtin_amdgcn_mfma_f32_16x16x32_bf16(a, bfr, c[mm], 0, 0, 0);
            }
        }
        if (r < 4) {
            const float bo_l = box_bo[r];
            const float inv  = 1.0f / (float)dim;
            #pragma unroll
            for (int mm = 0; mm < 2; ++mm)
                #pragma unroll
                for (int jj = 0; jj < 4; ++jj) {
                    const int t = (m0 + mm) * 16 + q * 4 + jj;
                    const int p = p0 + t;
                    const float d = tanhf(c[mm][jj] + bo_l);
                    float val;
                    if (r == 0)      val = ((float)(p & (dim - 1)) + 0.5f) * inv + 0.1f * d;
                    else if (r == 1) val = ((float)(p >> ls) + 0.5f) * inv + 0.1f * d;
                    else             val = exp2f(d) * inv;
                    out[((size_t)b * NTOK + n0 + t) * 84 + 80 + r] = val;
                }
        }
    }
}

extern "C" void kernel_launch(void* const* d_in, const int* in_sizes, int n_in,
                              void* d_out, int out_size, void* d_ws, size_t ws_size,
                              hipStream_t stream) {
    uint16_t* ws = (uint16_t*)d_ws;
    prep_weights<<<608, 256, 0, stream>>>(
        (const float*)d_in[5],  (const float*)d_in[7],
        (const float*)d_in[9],  (const float*)d_in[11], ws);
    dim3 grid(NTOK / 64, 8);   // 341 x 8 blocks, 512 threads
    dfd_fused<<<grid, 512, 0, stream>>>(
        (const float*)d_in[0], (const float*)d_in[1], (const float*)d_in[2],
        (const float*)d_in[3], (const float*)d_in[4],
        (const float*)d_in[6],  (const float*)d_in[8],
        (const float*)d_in[10], (const float*)d_in[12],
        ws, (float*)d_out);
}